// Round 5
// baseline (190.251 us; speedup 1.0000x reference)
//
#include <hip/hip_runtime.h>
#include <math.h>

#define N_NODES 4096
#define F_IN    512
#define F_OUT   64
#define ALPHA   0.2f
#define NPART   8

typedef _Float16 half8 __attribute__((ext_vector_type(8)));
typedef _Float16 half4 __attribute__((ext_vector_type(4)));
typedef float    floatx4 __attribute__((ext_vector_type(4)));

union H8U4 { half8 h; uint32_t u[4]; };

// async global->LDS DMA, 16B per lane, dest = lds_base + lane*16 (wave-uniform base)
__device__ __forceinline__ void async_copy16(void* lds, const void* g) {
    __builtin_amdgcn_global_load_lds(
        (const __attribute__((address_space(1))) unsigned int*)g,
        (__attribute__((address_space(3))) unsigned int*)lds, 16, 0, 0);
}

// ---------------- k_hW: h = x@W via MFMA, K-split across 8 waves; W gathered on the fly ----------------
// (k_prep eliminated — W-column gather verified numerically in round 3.)
// Also zeroes the 64 per-row-group completion counters for k_main's atomic tail.
__global__ __launch_bounds__(512) void k_hW(const float* __restrict__ x,
                                            const float* __restrict__ W,
                                            const float* __restrict__ a,
                                            float* __restrict__ h,
                                            _Float16* __restrict__ hT,
                                            float* __restrict__ e1,
                                            int* __restrict__ flags) {
    __shared__ float red[8][16][64];   // [wave][g4*4+r][lane]  32 KB
    int tid  = threadIdx.x;
    int lane = tid & 63;
    int w    = tid >> 6;               // 0..7
    int i0   = blockIdx.x * 16;
    int n    = lane & 15;
    int quad = lane >> 4;

    // re-zero completion counters (workspace is poisoned between iterations)
    if (blockIdx.x == 0 && tid < 64) flags[tid] = 0;

    floatx4 acc[4] = {{0,0,0,0},{0,0,0,0},{0,0,0,0},{0,0,0,0}};

    const float* xr = x + (size_t)(i0 + n) * F_IN + w * 64 + quad * 8;
#pragma unroll
    for (int kk = 0; kk < 64; kk += 32) {
        float4 x0 = *(const float4*)(xr + kk);
        float4 x1 = *(const float4*)(xr + kk + 4);
        half8 af = {(_Float16)x0.x, (_Float16)x0.y, (_Float16)x0.z, (_Float16)x0.w,
                    (_Float16)x1.x, (_Float16)x1.y, (_Float16)x1.z, (_Float16)x1.w};
        int k0 = w * 64 + kk + quad * 8;
#pragma unroll
        for (int g = 0; g < 4; ++g) {
            const float* wc = W + (size_t)k0 * F_OUT + g * 16 + n;   // column t = g*16+n
            half8 bf = {(_Float16)wc[0 * 64], (_Float16)wc[1 * 64], (_Float16)wc[2 * 64], (_Float16)wc[3 * 64],
                        (_Float16)wc[4 * 64], (_Float16)wc[5 * 64], (_Float16)wc[6 * 64], (_Float16)wc[7 * 64]};
            acc[g] = __builtin_amdgcn_mfma_f32_16x16x32_f16(af, bf, acc[g], 0, 0, 0);
        }
    }
#pragma unroll
    for (int g = 0; g < 4; ++g)
#pragma unroll
        for (int r = 0; r < 4; ++r)
            red[w][g * 4 + r][lane] = acc[g][r];
    __syncthreads();
    if (w != 0) return;
#pragma unroll
    for (int g = 0; g < 4; ++g)
#pragma unroll
        for (int r = 0; r < 4; ++r) {
            float v = 0.f;
#pragma unroll
            for (int ww = 0; ww < 8; ++ww)
                v += red[ww][g * 4 + r][lane];
            acc[g][r] = v;
        }
#pragma unroll
    for (int g = 0; g < 4; ++g) {
        half4 hv;
#pragma unroll
        for (int r = 0; r < 4; ++r) {
            h[(size_t)(i0 + quad * 4 + r) * F_OUT + g * 16 + n] = acc[g][r];
            hv[r] = (_Float16)acc[g][r];
        }
        *(half4*)(hT + (size_t)(g * 16 + n) * N_NODES + i0 + quad * 4) = hv;
    }
    float a1v[4];
#pragma unroll
    for (int g = 0; g < 4; ++g) a1v[g] = a[g * 16 + n];
#pragma unroll
    for (int r = 0; r < 4; ++r) {
        float v = acc[0][r] * a1v[0] + acc[1][r] * a1v[1] + acc[2][r] * a1v[2] + acc[3][r] * a1v[3];
        v += __shfl_xor(v, 1, 64);
        v += __shfl_xor(v, 2, 64);
        v += __shfl_xor(v, 4, 64);
        v += __shfl_xor(v, 8, 64);
        if (n == 0) e1[i0 + quad * 4 + r] = v;
    }
}

// ---------------- k_main: round-0 body VERBATIM + last-block-done reduction tail ----------------
// grid 512: b -> rb = b>>3 (64-row block), s = b&7 (512-col superchunk = 4x128).
// Tail: each block stores its partial, __threadfence(), atomicAdd on flags[rb];
// the 8th arrival reduces all partials and writes out (k_out dispatch eliminated).
__global__ __launch_bounds__(256, 3) void k_main(const int* __restrict__ adj,
                                                 const float* __restrict__ h,
                                                 const float* __restrict__ e1,
                                                 const float* __restrict__ a,
                                                 const _Float16* __restrict__ hT,
                                                 float* __restrict__ out_part,
                                                 float* __restrict__ den_part,
                                                 int* __restrict__ flags,
                                                 const float* __restrict__ bias,
                                                 float* __restrict__ out) {
    __shared__ int      lds_adj[4][8][256];   // 32 KB
    __shared__ _Float16 lds_B[16][512];       // 16 KB
    __shared__ _Float16 lds_P[512];           //  1 KB
    __shared__ float    lds_part[4][64];      //  1 KB
    __shared__ float    TqS[64];
    __shared__ int      is_last;

    int tid  = threadIdx.x;
    int lane = tid & 63;
    int w    = tid >> 6;
    int b    = blockIdx.x;
    int rb   = b >> 3;
    int s    = b & 7;
    int i0   = rb * 64 + w * 16;
    int n    = lane & 15;
    int quad = lane >> 4;

    // ---- prologue: Tq[rb][t] = sum_r a2[r] * h[(r*64+rb)*64 + t] ----
    {
        int t  = tid & 63;
        int rp = tid >> 6;
        const float* a2 = a + F_OUT;
        float ssum = 0.f;
#pragma unroll
        for (int rr = 0; rr < 16; ++rr) {
            int r = rp * 16 + rr;
            ssum += a2[r] * h[(size_t)r * 4096 + rb * 64 + t];
        }
        lds_part[rp][t] = ssum;
    }
    __syncthreads();
    if (tid < 64)
        TqS[tid] = lds_part[0][tid] + lds_part[1][tid] + lds_part[2][tid] + lds_part[3][tid];
    __syncthreads();
    {
        int j = s * 512 + tid * 2;
        float2 ev = *(const float2*)(e1 + j);
        float e0 = ev.x + TqS[(tid * 2) & 63];
        float e1v = ev.y + TqS[(tid * 2 + 1) & 63];
        e0  = e0  > 0.f ? e0  : ALPHA * e0;
        e1v = e1v > 0.f ? e1v : ALPHA * e1v;
        lds_P[tid * 2]     = (_Float16)__expf(e0);
        lds_P[tid * 2 + 1] = (_Float16)__expf(e1v);
    }
    // first use of lds_P is after the first chunk's __syncthreads()

    floatx4 acc[4] = {{0,0,0,0},{0,0,0,0},{0,0,0,0},{0,0,0,0}};
    floatx4 accd = {0, 0, 0, 0};
    _Float16 one_h = (n == 0) ? (_Float16)1.0f : (_Float16)0.0f;
    half8 ones_f = {one_h, one_h, one_h, one_h, one_h, one_h, one_h, one_h};

    for (int it = 0; it < 4; ++it) {
        int jb = s * 512 + it * 128;
        const int* adj_base = adj + (size_t)(i0 + n) * N_NODES + jb + quad * 8;
#pragma unroll
        for (int c = 0; c < 4; ++c) {
            async_copy16(&lds_adj[w][c * 2 + 0][0], adj_base + c * 32);
            async_copy16(&lds_adj[w][c * 2 + 1][0], adj_base + c * 32 + 4);
        }
        const _Float16* hT_base = hT + (size_t)(w * 16 + n) * N_NODES + jb + quad * 8;
#pragma unroll
        for (int c = 0; c < 4; ++c)
            async_copy16(&lds_B[w * 4 + c][0], hT_base + c * 32);
        __syncthreads();

#pragma unroll
        for (int c = 0; c < 4; ++c) {
            int4 ga = *(const int4*)&lds_adj[w][c * 2 + 0][lane * 4];
            int4 gb = *(const int4*)&lds_adj[w][c * 2 + 1][lane * 4];
            H8U4 pv, af;
            pv.h = *(const half8*)&lds_P[it * 128 + c * 32 + quad * 8];
            af.u[0] = pv.u[0] & ((ga.x > 0 ? 0x0000FFFFu : 0u) | (ga.y > 0 ? 0xFFFF0000u : 0u));
            af.u[1] = pv.u[1] & ((ga.z > 0 ? 0x0000FFFFu : 0u) | (ga.w > 0 ? 0xFFFF0000u : 0u));
            af.u[2] = pv.u[2] & ((gb.x > 0 ? 0x0000FFFFu : 0u) | (gb.y > 0 ? 0xFFFF0000u : 0u));
            af.u[3] = pv.u[3] & ((gb.z > 0 ? 0x0000FFFFu : 0u) | (gb.w > 0 ? 0xFFFF0000u : 0u));
#pragma unroll
            for (int g4 = 0; g4 < 4; ++g4) {
                half8 bf = *(const half8*)&lds_B[g4 * 4 + c][lane * 8];
                acc[g4] = __builtin_amdgcn_mfma_f32_16x16x32_f16(af.h, bf, acc[g4], 0, 0, 0);
            }
            accd = __builtin_amdgcn_mfma_f32_16x16x32_f16(af.h, ones_f, accd, 0, 0, 0);
        }
        __syncthreads();
    }

    // ---- store this superchunk's private partial (C: row = quad*4+r, col = g4*16+n) ----
    float* op = out_part + ((size_t)s * N_NODES + i0) * F_OUT;
#pragma unroll
    for (int g4 = 0; g4 < 4; ++g4)
#pragma unroll
        for (int r = 0; r < 4; ++r)
            op[(quad * 4 + r) * F_OUT + g4 * 16 + n] = acc[g4][r];
    if (n == 0) {
#pragma unroll
        for (int r = 0; r < 4; ++r)
            den_part[s * N_NODES + i0 + quad * 4 + r] = accd[r];
    }

    // ---- last-block-done tail: 8th superchunk block of this row group reduces & writes out ----
    __threadfence();                       // release: partials visible device-wide
    if (tid == 0)
        is_last = (atomicAdd(&flags[rb], 1) == NPART - 1);
    __syncthreads();
    if (!is_last) return;
    __threadfence();                       // acquire: other blocks' partials now visible

    int i0g = rb * 64;
#pragma unroll
    for (int e = tid; e < 1024; e += 256) {    // 64 rows x 16 float4-cols
        int row = e >> 4;
        int c4  = e & 15;
        float4 sacc = {0.f, 0.f, 0.f, 0.f};
        float dacc = 0.f;
#pragma unroll
        for (int p = 0; p < NPART; ++p) {
            float4 v = *(const float4*)(out_part + ((size_t)p * N_NODES + i0g + row) * F_OUT + c4 * 4);
            sacc.x += v.x; sacc.y += v.y; sacc.z += v.z; sacc.w += v.w;
            dacc += den_part[p * N_NODES + i0g + row];
        }
        float4 bv = *(const float4*)(bias + c4 * 4);
        float4 o;
        o.x = fmaxf(sacc.x / dacc, 0.f) + bv.x;
        o.y = fmaxf(sacc.y / dacc, 0.f) + bv.y;
        o.z = fmaxf(sacc.z / dacc, 0.f) + bv.z;
        o.w = fmaxf(sacc.w / dacc, 0.f) + bv.w;
        *(float4*)(out + (size_t)(i0g + row) * F_OUT + c4 * 4) = o;
    }
}

extern "C" void kernel_launch(void* const* d_in, const int* in_sizes, int n_in,
                              void* d_out, int out_size, void* d_ws, size_t ws_size,
                              hipStream_t stream) {
    const float* x    = (const float*)d_in[0];
    const int*   adj  = (const int*)d_in[1];
    const float* W    = (const float*)d_in[2];
    const float* a    = (const float*)d_in[3];
    const float* bias = (const float*)d_in[4];
    float* out = (float*)d_out;

    char* ws = (char*)d_ws;
    float*    h        = (float*)ws;                            // 1 MB
    _Float16* hT       = (_Float16*)(ws + 1024 * 1024);         // 512 KB
    float*    e1       = (float*)(ws + 1536 * 1024);            // 16 KB
    float*    out_part = (float*)(ws + 2048 * 1024);            // 8 MB (NPART=8, fp32)
    float*    den_part = (float*)(ws + (2048 + 8192) * 1024);   // 128 KB
    int*      flags    = (int*)(ws + (2048 + 8192 + 128) * 1024); // 256 B

    k_hW  <<<256, 512, 0, stream>>>(x, W, a, h, hT, e1, flags);
    k_main<<<512, 256, 0, stream>>>(adj, h, e1, a, hT, out_part, den_part, flags, bias, out);
}

// Round 6
// 121.956 us; speedup vs baseline: 1.5600x; 1.5600x over previous
//
#include <hip/hip_runtime.h>
#include <math.h>

#define N_NODES 4096
#define F_IN    512
#define F_OUT   64
#define ALPHA   0.2f
#define NPART   8

typedef _Float16 half8 __attribute__((ext_vector_type(8)));
typedef _Float16 half4 __attribute__((ext_vector_type(4)));
typedef float    floatx4 __attribute__((ext_vector_type(4)));

union H8U4 { half8 h; uint32_t u[4]; };

// async global->LDS DMA, 16B per lane, dest = lds_base + lane*16 (wave-uniform base)
__device__ __forceinline__ void async_copy16(void* lds, const void* g) {
    __builtin_amdgcn_global_load_lds(
        (const __attribute__((address_space(1))) unsigned int*)g,
        (__attribute__((address_space(3))) unsigned int*)lds, 16, 0, 0);
}

// ---------------- k_prep2: adj -> 1-bit mask (2 MB) + WT transpose, one dispatch ----------------
// blocks 0..2047: word wid covers adj[wid*32 .. wid*32+32); bit j = adj[wid*32+j] > 0.
// blocks 2048..2175: WT[t][k] = f16(W[k][t]).
__global__ __launch_bounds__(256) void k_prep2(const float* __restrict__ W,
                                               _Float16* __restrict__ WT,
                                               const int* __restrict__ adj,
                                               uint32_t* __restrict__ bm) {
    int gb = blockIdx.x;
    if (gb < 2048) {
        int wid = gb * 256 + threadIdx.x;          // 0..524287 bitmap words
        const int* p = adj + (size_t)wid * 32;
        uint32_t m = 0;
#pragma unroll
        for (int q = 0; q < 8; ++q) {
            int4 v = *(const int4*)(p + q * 4);
            m |= (v.x > 0 ? 1u : 0u) << (q * 4 + 0);
            m |= (v.y > 0 ? 1u : 0u) << (q * 4 + 1);
            m |= (v.z > 0 ? 1u : 0u) << (q * 4 + 2);
            m |= (v.w > 0 ? 1u : 0u) << (q * 4 + 3);
        }
        bm[wid] = m;
    } else {
        int idx = (gb - 2048) * 256 + threadIdx.x; // 32768 WT elements
        int t = idx >> 9;
        int k = idx & 511;
        WT[idx] = (_Float16)W[k * F_OUT + t];
    }
}

// ---------------- k_hW: h = x@W via MFMA, K-split across 8 waves (512-thr blocks) ----------------
__global__ __launch_bounds__(512) void k_hW(const float* __restrict__ x,
                                            const _Float16* __restrict__ WT,
                                            const float* __restrict__ a,
                                            float* __restrict__ h,
                                            _Float16* __restrict__ hT,
                                            float* __restrict__ e1) {
    __shared__ float red[8][16][64];   // [wave][g4*4+r][lane]  32 KB
    int tid  = threadIdx.x;
    int lane = tid & 63;
    int w    = tid >> 6;               // 0..7
    int i0   = blockIdx.x * 16;
    int n    = lane & 15;
    int quad = lane >> 4;

    floatx4 acc[4] = {{0,0,0,0},{0,0,0,0},{0,0,0,0},{0,0,0,0}};

    const float* xr = x + (size_t)(i0 + n) * F_IN + w * 64 + quad * 8;
    const _Float16* wb = WT + w * 64 + quad * 8;
#pragma unroll
    for (int kk = 0; kk < 64; kk += 32) {
        float4 x0 = *(const float4*)(xr + kk);
        float4 x1 = *(const float4*)(xr + kk + 4);
        half8 af = {(_Float16)x0.x, (_Float16)x0.y, (_Float16)x0.z, (_Float16)x0.w,
                    (_Float16)x1.x, (_Float16)x1.y, (_Float16)x1.z, (_Float16)x1.w};
#pragma unroll
        for (int g = 0; g < 4; ++g) {
            half8 bf = *(const half8*)(wb + (size_t)(g * 16 + n) * F_IN + kk);
            acc[g] = __builtin_amdgcn_mfma_f32_16x16x32_f16(af, bf, acc[g], 0, 0, 0);
        }
    }
#pragma unroll
    for (int g = 0; g < 4; ++g)
#pragma unroll
        for (int r = 0; r < 4; ++r)
            red[w][g * 4 + r][lane] = acc[g][r];
    __syncthreads();
    if (w != 0) return;
#pragma unroll
    for (int g = 0; g < 4; ++g)
#pragma unroll
        for (int r = 0; r < 4; ++r) {
            float v = 0.f;
#pragma unroll
            for (int ww = 0; ww < 8; ++ww)
                v += red[ww][g * 4 + r][lane];
            acc[g][r] = v;
        }
#pragma unroll
    for (int g = 0; g < 4; ++g) {
        half4 hv;
#pragma unroll
        for (int r = 0; r < 4; ++r) {
            h[(size_t)(i0 + quad * 4 + r) * F_OUT + g * 16 + n] = acc[g][r];
            hv[r] = (_Float16)acc[g][r];
        }
        *(half4*)(hT + (size_t)(g * 16 + n) * N_NODES + i0 + quad * 4) = hv;
    }
    float a1v[4];
#pragma unroll
    for (int g = 0; g < 4; ++g) a1v[g] = a[g * 16 + n];
#pragma unroll
    for (int r = 0; r < 4; ++r) {
        float v = acc[0][r] * a1v[0] + acc[1][r] * a1v[1] + acc[2][r] * a1v[2] + acc[3][r] * a1v[3];
        v += __shfl_xor(v, 1, 64);
        v += __shfl_xor(v, 2, 64);
        v += __shfl_xor(v, 4, 64);
        v += __shfl_xor(v, 8, 64);
        if (n == 0) e1[i0 + quad * 4 + r] = v;
    }
}

// ---------------- k_main: R0 structure, adj replaced by pre-loaded 1-bit mask ----------------
// grid 512: b -> rb = b>>3 (64-row block), s = b&7 (512-col superchunk = 4x128).
// Each lane pre-loads its 16 bitmap words (64 B) covering its row x 512 cols before the loop;
// per-iter DMA drops 12 -> 4 (hT only); lds_adj (32 KB) deleted.
__global__ __launch_bounds__(256, 3) void k_main(const uint32_t* __restrict__ bm,
                                                 const float* __restrict__ h,
                                                 const float* __restrict__ e1,
                                                 const float* __restrict__ a,
                                                 const _Float16* __restrict__ hT,
                                                 float* __restrict__ out_part,
                                                 float* __restrict__ den_part) {
    __shared__ _Float16 lds_B[16][512];       // 16 KB
    __shared__ _Float16 lds_P[512];           //  1 KB
    __shared__ float    lds_part[4][64];      //  1 KB
    __shared__ float    TqS[64];

    int tid  = threadIdx.x;
    int lane = tid & 63;
    int w    = tid >> 6;
    int b    = blockIdx.x;
    int rb   = b >> 3;
    int s    = b & 7;
    int i0   = rb * 64 + w * 16;
    int n    = lane & 15;
    int quad = lane >> 4;

    // ---- pre-load this lane's bitmap row-slice: row i0+n, cols s*512..s*512+511 = 16 words ----
    const uint32_t* bmr = bm + (size_t)(i0 + n) * (N_NODES / 32) + s * 16;
    uint4 bwa = *(const uint4*)(bmr + 0);
    uint4 bwb = *(const uint4*)(bmr + 4);
    uint4 bwc = *(const uint4*)(bmr + 8);
    uint4 bwd = *(const uint4*)(bmr + 12);
    uint32_t bw[16] = {bwa.x, bwa.y, bwa.z, bwa.w, bwb.x, bwb.y, bwb.z, bwb.w,
                       bwc.x, bwc.y, bwc.z, bwc.w, bwd.x, bwd.y, bwd.z, bwd.w};

    // ---- prologue: Tq[rb][t] = sum_r a2[r] * h[(r*64+rb)*64 + t] ----
    {
        int t  = tid & 63;
        int rp = tid >> 6;
        const float* a2 = a + F_OUT;
        float ssum = 0.f;
#pragma unroll
        for (int rr = 0; rr < 16; ++rr) {
            int r = rp * 16 + rr;
            ssum += a2[r] * h[(size_t)r * 4096 + rb * 64 + t];
        }
        lds_part[rp][t] = ssum;
    }
    __syncthreads();
    if (tid < 64)
        TqS[tid] = lds_part[0][tid] + lds_part[1][tid] + lds_part[2][tid] + lds_part[3][tid];
    __syncthreads();
    {
        int j = s * 512 + tid * 2;
        float2 ev = *(const float2*)(e1 + j);
        float e0 = ev.x + TqS[(tid * 2) & 63];
        float e1v = ev.y + TqS[(tid * 2 + 1) & 63];
        e0  = e0  > 0.f ? e0  : ALPHA * e0;
        e1v = e1v > 0.f ? e1v : ALPHA * e1v;
        lds_P[tid * 2]     = (_Float16)__expf(e0);
        lds_P[tid * 2 + 1] = (_Float16)__expf(e1v);
    }
    // first use of lds_P is after the first chunk's __syncthreads()

    floatx4 acc[4] = {{0,0,0,0},{0,0,0,0},{0,0,0,0},{0,0,0,0}};
    floatx4 accd = {0, 0, 0, 0};
    _Float16 one_h = (n == 0) ? (_Float16)1.0f : (_Float16)0.0f;
    half8 ones_f = {one_h, one_h, one_h, one_h, one_h, one_h, one_h, one_h};

#pragma unroll
    for (int it = 0; it < 4; ++it) {
        int jb = s * 512 + it * 128;
        const _Float16* hT_base = hT + (size_t)(w * 16 + n) * N_NODES + jb + quad * 8;
#pragma unroll
        for (int c = 0; c < 4; ++c)
            async_copy16(&lds_B[w * 4 + c][0], hT_base + c * 32);
        __syncthreads();

#pragma unroll
        for (int c = 0; c < 4; ++c) {
            // mask bits for row i0+n, cols jb + c*32 + quad*8 .. +7
            uint32_t mbyte = bw[it * 4 + c] >> (quad * 8);
            H8U4 pv, af;
            pv.h = *(const half8*)&lds_P[it * 128 + c * 32 + quad * 8];
            af.u[0] = pv.u[0] & (((mbyte &   1u) ? 0x0000FFFFu : 0u) | ((mbyte &   2u) ? 0xFFFF0000u : 0u));
            af.u[1] = pv.u[1] & (((mbyte &   4u) ? 0x0000FFFFu : 0u) | ((mbyte &   8u) ? 0xFFFF0000u : 0u));
            af.u[2] = pv.u[2] & (((mbyte &  16u) ? 0x0000FFFFu : 0u) | ((mbyte &  32u) ? 0xFFFF0000u : 0u));
            af.u[3] = pv.u[3] & (((mbyte &  64u) ? 0x0000FFFFu : 0u) | ((mbyte & 128u) ? 0xFFFF0000u : 0u));
#pragma unroll
            for (int g4 = 0; g4 < 4; ++g4) {
                half8 bf = *(const half8*)&lds_B[g4 * 4 + c][lane * 8];
                acc[g4] = __builtin_amdgcn_mfma_f32_16x16x32_f16(af.h, bf, acc[g4], 0, 0, 0);
            }
            accd = __builtin_amdgcn_mfma_f32_16x16x32_f16(af.h, ones_f, accd, 0, 0, 0);
        }
        __syncthreads();
    }

    // ---- store this superchunk's private partial (C: row = quad*4+r, col = g4*16+n) ----
    float* op = out_part + ((size_t)s * N_NODES + i0) * F_OUT;
#pragma unroll
    for (int g4 = 0; g4 < 4; ++g4)
#pragma unroll
        for (int r = 0; r < 4; ++r)
            op[(quad * 4 + r) * F_OUT + g4 * 16 + n] = acc[g4][r];
    if (n == 0) {
#pragma unroll
        for (int r = 0; r < 4; ++r)
            den_part[s * N_NODES + i0 + quad * 4 + r] = accd[r];
    }
}

// ---------------- k_out: out = relu(sum_s out_part / sum_s den_part) + bias (float4) ----------------
__global__ __launch_bounds__(128) void k_out(const float* __restrict__ out_part,
                                             const float* __restrict__ den_part,
                                             const float* __restrict__ bias,
                                             float* __restrict__ out) {
    int idx4 = blockIdx.x * 128 + threadIdx.x;   // 65536 float4s
    int base = idx4 * 4;
    int i = base >> 6;
    int t = base & 63;
    float4 sacc = {0.f, 0.f, 0.f, 0.f};
    float dacc = 0.f;
#pragma unroll
    for (int p = 0; p < NPART; ++p) {
        float4 v = ((const float4*)(out_part + (size_t)p * N_NODES * F_OUT))[idx4];
        sacc.x += v.x; sacc.y += v.y; sacc.z += v.z; sacc.w += v.w;
        dacc += den_part[p * N_NODES + i];
    }
    float4 bv = *(const float4*)(bias + t);
    float4 o;
    o.x = fmaxf(sacc.x / dacc, 0.f) + bv.x;
    o.y = fmaxf(sacc.y / dacc, 0.f) + bv.y;
    o.z = fmaxf(sacc.z / dacc, 0.f) + bv.z;
    o.w = fmaxf(sacc.w / dacc, 0.f) + bv.w;
    ((float4*)out)[idx4] = o;
}

extern "C" void kernel_launch(void* const* d_in, const int* in_sizes, int n_in,
                              void* d_out, int out_size, void* d_ws, size_t ws_size,
                              hipStream_t stream) {
    const float* x    = (const float*)d_in[0];
    const int*   adj  = (const int*)d_in[1];
    const float* W    = (const float*)d_in[2];
    const float* a    = (const float*)d_in[3];
    const float* bias = (const float*)d_in[4];
    float* out = (float*)d_out;

    char* ws = (char*)d_ws;
    float*    h        = (float*)ws;                            // 1 MB
    _Float16* hT       = (_Float16*)(ws + 1024 * 1024);         // 512 KB
    float*    e1       = (float*)(ws + 1536 * 1024);            // 16 KB
    _Float16* WT       = (_Float16*)(ws + 1552 * 1024);         // 64 KB
    uint32_t* bm       = (uint32_t*)(ws + 2128 * 1024);         // 2 MB bitmap
    float*    out_part = (float*)(ws + 4176 * 1024);            // 8 MB (NPART=8, fp32)
    float*    den_part = (float*)(ws + (4176 + 8192) * 1024);   // 128 KB

    k_prep2<<<2176, 256, 0, stream>>>(W, WT, adj, bm);
    k_hW   <<<256, 512, 0, stream>>>(x, WT, a, h, hT, e1);
    k_main <<<512, 256, 0, stream>>>(bm, h, e1, a, hT, out_part, den_part);
    k_out  <<<512, 128, 0, stream>>>(out_part, den_part, bias, out);
}

// Round 7
// 120.930 us; speedup vs baseline: 1.5732x; 1.0085x over previous
//
#include <hip/hip_runtime.h>
#include <math.h>

#define N_NODES 4096
#define F_IN    512
#define F_OUT   64
#define ALPHA   0.2f
#define NPART   8

typedef _Float16 half8 __attribute__((ext_vector_type(8)));
typedef _Float16 half4 __attribute__((ext_vector_type(4)));
typedef float    floatx4 __attribute__((ext_vector_type(4)));

union H8U4 { half8 h; uint32_t u[4]; };

// async global->LDS DMA, 16B per lane, dest = lds_base + lane*16 (wave-uniform base)
__device__ __forceinline__ void async_copy16(void* lds, const void* g) {
    __builtin_amdgcn_global_load_lds(
        (const __attribute__((address_space(1))) unsigned int*)g,
        (__attribute__((address_space(3))) unsigned int*)lds, 16, 0, 0);
}

// ---------------- k_pre: FUSED bitmap-pack + hW (one dispatch, heterogeneous blocks) ----------------
// blocks 0..1023   : adj -> 1-bit mask. thread -> word wid = gb*512+tid; reads adj[wid*32..+32)
//                    (128 B contiguous per lane, fully coalesced), writes bm[wid].
// blocks 1024..1279: h = x@W via MFMA, K-split across 8 waves; W columns gathered on the fly
//                    (R3/R5-verified, bit-identical to the WT path). Also writes hT, e1.
__global__ __launch_bounds__(512) void k_pre(const float* __restrict__ x,
                                             const int* __restrict__ adj,
                                             const float* __restrict__ W,
                                             const float* __restrict__ a,
                                             uint32_t* __restrict__ bm,
                                             float* __restrict__ h,
                                             _Float16* __restrict__ hT,
                                             float* __restrict__ e1) {
    __shared__ float red[8][16][64];   // used by hW blocks only (32 KB)
    int gb  = blockIdx.x;
    int tid = threadIdx.x;

    if (gb < 1024) {   // ---- bitmap pack ----
        int wid = gb * 512 + tid;                  // 524288 words total
        const int* p = adj + (size_t)wid * 32;
        uint32_t m = 0;
#pragma unroll
        for (int q = 0; q < 8; ++q) {
            int4 v = *(const int4*)(p + q * 4);
            m |= (v.x > 0 ? 1u : 0u) << (q * 4 + 0);
            m |= (v.y > 0 ? 1u : 0u) << (q * 4 + 1);
            m |= (v.z > 0 ? 1u : 0u) << (q * 4 + 2);
            m |= (v.w > 0 ? 1u : 0u) << (q * 4 + 3);
        }
        bm[wid] = m;
        return;
    }

    // ---- hW part ----
    int lane = tid & 63;
    int w    = tid >> 6;               // 0..7
    int i0   = (gb - 1024) * 16;
    int n    = lane & 15;
    int quad = lane >> 4;

    floatx4 acc[4] = {{0,0,0,0},{0,0,0,0},{0,0,0,0},{0,0,0,0}};

    const float* xr = x + (size_t)(i0 + n) * F_IN + w * 64 + quad * 8;
#pragma unroll
    for (int kk = 0; kk < 64; kk += 32) {
        float4 x0 = *(const float4*)(xr + kk);
        float4 x1 = *(const float4*)(xr + kk + 4);
        half8 af = {(_Float16)x0.x, (_Float16)x0.y, (_Float16)x0.z, (_Float16)x0.w,
                    (_Float16)x1.x, (_Float16)x1.y, (_Float16)x1.z, (_Float16)x1.w};
        int k0 = w * 64 + kk + quad * 8;
#pragma unroll
        for (int g = 0; g < 4; ++g) {
            const float* wc = W + (size_t)k0 * F_OUT + g * 16 + n;   // column t = g*16+n
            half8 bf = {(_Float16)wc[0 * 64], (_Float16)wc[1 * 64], (_Float16)wc[2 * 64], (_Float16)wc[3 * 64],
                        (_Float16)wc[4 * 64], (_Float16)wc[5 * 64], (_Float16)wc[6 * 64], (_Float16)wc[7 * 64]};
            acc[g] = __builtin_amdgcn_mfma_f32_16x16x32_f16(af, bf, acc[g], 0, 0, 0);
        }
    }
#pragma unroll
    for (int g = 0; g < 4; ++g)
#pragma unroll
        for (int r = 0; r < 4; ++r)
            red[w][g * 4 + r][lane] = acc[g][r];
    __syncthreads();
    if (w != 0) return;
#pragma unroll
    for (int g = 0; g < 4; ++g)
#pragma unroll
        for (int r = 0; r < 4; ++r) {
            float v = 0.f;
#pragma unroll
            for (int ww = 0; ww < 8; ++ww)
                v += red[ww][g * 4 + r][lane];
            acc[g][r] = v;
        }
#pragma unroll
    for (int g = 0; g < 4; ++g) {
        half4 hv;
#pragma unroll
        for (int r = 0; r < 4; ++r) {
            h[(size_t)(i0 + quad * 4 + r) * F_OUT + g * 16 + n] = acc[g][r];
            hv[r] = (_Float16)acc[g][r];
        }
        *(half4*)(hT + (size_t)(g * 16 + n) * N_NODES + i0 + quad * 4) = hv;
    }
    float a1v[4];
#pragma unroll
    for (int g = 0; g < 4; ++g) a1v[g] = a[g * 16 + n];
#pragma unroll
    for (int r = 0; r < 4; ++r) {
        float v = acc[0][r] * a1v[0] + acc[1][r] * a1v[1] + acc[2][r] * a1v[2] + acc[3][r] * a1v[3];
        v += __shfl_xor(v, 1, 64);
        v += __shfl_xor(v, 2, 64);
        v += __shfl_xor(v, 4, 64);
        v += __shfl_xor(v, 8, 64);
        if (n == 0) e1[i0 + quad * 4 + r] = v;
    }
}

// ---------------- k_main: SINGLE-STAGE bitmap-masked MFMA ----------------
// grid 512: b -> rb = b>>3 (64-row block), s = b&7 (512-col superchunk).
// All 16 hT DMAs issued at kernel ENTRY (latency hides under the Tq/P prologue);
// ONE barrier after the P-write (drains DMAs + makes P visible); then all 80 MFMAs
// run barrier-free. lds_adj gone (1-bit mask pre-loaded to registers, R6-verified).
__global__ __launch_bounds__(256, 2) void k_main(const uint32_t* __restrict__ bm,
                                                 const float* __restrict__ h,
                                                 const float* __restrict__ e1,
                                                 const float* __restrict__ a,
                                                 const _Float16* __restrict__ hT,
                                                 float* __restrict__ out_part,
                                                 float* __restrict__ den_part) {
    __shared__ _Float16 lds_B[4][16][512];    // 64 KB (all 4 k-chunks resident)
    __shared__ _Float16 lds_P[512];           //  1 KB
    __shared__ float    lds_part[4][64];      //  1 KB
    __shared__ float    TqS[64];              //  0.25 KB

    int tid  = threadIdx.x;
    int lane = tid & 63;
    int w    = tid >> 6;
    int b    = blockIdx.x;
    int rb   = b >> 3;
    int s    = b & 7;
    int i0   = rb * 64 + w * 16;
    int n    = lane & 15;
    int quad = lane >> 4;

    // ---- issue ALL hT staging DMAs up front ----
#pragma unroll
    for (int it = 0; it < 4; ++it) {
        int jb = s * 512 + it * 128;
        const _Float16* hT_base = hT + (size_t)(w * 16 + n) * N_NODES + jb + quad * 8;
#pragma unroll
        for (int c = 0; c < 4; ++c)
            async_copy16(&lds_B[it][w * 4 + c][0], hT_base + c * 32);
    }

    // ---- pre-load this lane's bitmap row-slice: row i0+n, cols s*512..+511 = 16 words ----
    const uint32_t* bmr = bm + (size_t)(i0 + n) * (N_NODES / 32) + s * 16;
    uint4 bwa = *(const uint4*)(bmr + 0);
    uint4 bwb = *(const uint4*)(bmr + 4);
    uint4 bwc = *(const uint4*)(bmr + 8);
    uint4 bwd = *(const uint4*)(bmr + 12);
    uint32_t bw[16] = {bwa.x, bwa.y, bwa.z, bwa.w, bwb.x, bwb.y, bwb.z, bwb.w,
                       bwc.x, bwc.y, bwc.z, bwc.w, bwd.x, bwd.y, bwd.z, bwd.w};

    // ---- prologue: Tq[rb][t] = sum_r a2[r] * h[(r*64+rb)*64 + t] ----
    {
        int t  = tid & 63;
        int rp = tid >> 6;
        const float* a2 = a + F_OUT;
        float ssum = 0.f;
#pragma unroll
        for (int rr = 0; rr < 16; ++rr) {
            int r = rp * 16 + rr;
            ssum += a2[r] * h[(size_t)r * 4096 + rb * 64 + t];
        }
        lds_part[rp][t] = ssum;
    }
    __syncthreads();
    if (tid < 64)
        TqS[tid] = lds_part[0][tid] + lds_part[1][tid] + lds_part[2][tid] + lds_part[3][tid];
    __syncthreads();
    {
        int j = s * 512 + tid * 2;
        float2 ev = *(const float2*)(e1 + j);
        float e0 = ev.x + TqS[(tid * 2) & 63];
        float e1v = ev.y + TqS[(tid * 2 + 1) & 63];
        e0  = e0  > 0.f ? e0  : ALPHA * e0;
        e1v = e1v > 0.f ? e1v : ALPHA * e1v;
        lds_P[tid * 2]     = (_Float16)__expf(e0);
        lds_P[tid * 2 + 1] = (_Float16)__expf(e1v);
    }
    __syncthreads();   // P visible to all waves; also drains all staged DMAs (vmcnt(0) pre-barrier)

    floatx4 acc[4] = {{0,0,0,0},{0,0,0,0},{0,0,0,0},{0,0,0,0}};
    floatx4 accd = {0, 0, 0, 0};
    _Float16 one_h = (n == 0) ? (_Float16)1.0f : (_Float16)0.0f;
    half8 ones_f = {one_h, one_h, one_h, one_h, one_h, one_h, one_h, one_h};

    // ---- 16 compute groups, barrier-free ----
#pragma unroll
    for (int it = 0; it < 4; ++it) {
#pragma unroll
        for (int c = 0; c < 4; ++c) {
            // mask bits for row i0+n, cols s*512 + it*128 + c*32 + quad*8 .. +7
            uint32_t mbyte = bw[it * 4 + c] >> (quad * 8);
            H8U4 pv, af;
            pv.h = *(const half8*)&lds_P[it * 128 + c * 32 + quad * 8];
            af.u[0] = pv.u[0] & (((mbyte &   1u) ? 0x0000FFFFu : 0u) | ((mbyte &   2u) ? 0xFFFF0000u : 0u));
            af.u[1] = pv.u[1] & (((mbyte &   4u) ? 0x0000FFFFu : 0u) | ((mbyte &   8u) ? 0xFFFF0000u : 0u));
            af.u[2] = pv.u[2] & (((mbyte &  16u) ? 0x0000FFFFu : 0u) | ((mbyte &  32u) ? 0xFFFF0000u : 0u));
            af.u[3] = pv.u[3] & (((mbyte &  64u) ? 0x0000FFFFu : 0u) | ((mbyte & 128u) ? 0xFFFF0000u : 0u));
#pragma unroll
            for (int g4 = 0; g4 < 4; ++g4) {
                half8 bf = *(const half8*)&lds_B[it][g4 * 4 + c][lane * 8];
                acc[g4] = __builtin_amdgcn_mfma_f32_16x16x32_f16(af.h, bf, acc[g4], 0, 0, 0);
            }
            accd = __builtin_amdgcn_mfma_f32_16x16x32_f16(af.h, ones_f, accd, 0, 0, 0);
        }
    }

    // ---- store this superchunk's private partial (C: row = quad*4+r, col = g4*16+n) ----
    float* op = out_part + ((size_t)s * N_NODES + i0) * F_OUT;
#pragma unroll
    for (int g4 = 0; g4 < 4; ++g4)
#pragma unroll
        for (int r = 0; r < 4; ++r)
            op[(quad * 4 + r) * F_OUT + g4 * 16 + n] = acc[g4][r];
    if (n == 0) {
#pragma unroll
        for (int r = 0; r < 4; ++r)
            den_part[s * N_NODES + i0 + quad * 4 + r] = accd[r];
    }
}

// ---------------- k_out: out = relu(sum_s out_part / sum_s den_part) + bias (float4) ----------------
__global__ __launch_bounds__(128) void k_out(const float* __restrict__ out_part,
                                             const float* __restrict__ den_part,
                                             const float* __restrict__ bias,
                                             float* __restrict__ out) {
    int idx4 = blockIdx.x * 128 + threadIdx.x;   // 65536 float4s
    int base = idx4 * 4;
    int i = base >> 6;
    int t = base & 63;
    float4 sacc = {0.f, 0.f, 0.f, 0.f};
    float dacc = 0.f;
#pragma unroll
    for (int p = 0; p < NPART; ++p) {
        float4 v = ((const float4*)(out_part + (size_t)p * N_NODES * F_OUT))[idx4];
        sacc.x += v.x; sacc.y += v.y; sacc.z += v.z; sacc.w += v.w;
        dacc += den_part[p * N_NODES + i];
    }
    float4 bv = *(const float4*)(bias + t);
    float4 o;
    o.x = fmaxf(sacc.x / dacc, 0.f) + bv.x;
    o.y = fmaxf(sacc.y / dacc, 0.f) + bv.y;
    o.z = fmaxf(sacc.z / dacc, 0.f) + bv.z;
    o.w = fmaxf(sacc.w / dacc, 0.f) + bv.w;
    ((float4*)out)[idx4] = o;
}

extern "C" void kernel_launch(void* const* d_in, const int* in_sizes, int n_in,
                              void* d_out, int out_size, void* d_ws, size_t ws_size,
                              hipStream_t stream) {
    const float* x    = (const float*)d_in[0];
    const int*   adj  = (const int*)d_in[1];
    const float* W    = (const float*)d_in[2];
    const float* a    = (const float*)d_in[3];
    const float* bias = (const float*)d_in[4];
    float* out = (float*)d_out;

    char* ws = (char*)d_ws;
    float*    h        = (float*)ws;                            // 1 MB
    _Float16* hT       = (_Float16*)(ws + 1024 * 1024);         // 512 KB
    float*    e1       = (float*)(ws + 1536 * 1024);            // 16 KB
    uint32_t* bm       = (uint32_t*)(ws + 2128 * 1024);         // 2 MB bitmap
    float*    out_part = (float*)(ws + 4176 * 1024);            // 8 MB (NPART=8, fp32)
    float*    den_part = (float*)(ws + (4176 + 8192) * 1024);   // 128 KB

    k_pre <<<1280, 512, 0, stream>>>(x, adj, W, a, bm, h, hT, e1);
    k_main<<<512, 256, 0, stream>>>(bm, h, e1, a, hT, out_part, den_part);
    k_out <<<512, 128, 0, stream>>>(out_part, den_part, bias, out);
}